// Round 1
// baseline (454.528 us; speedup 1.0000x reference)
//
#include <hip/hip_runtime.h>

// Correlation cost volume: out[b,d,h,w] = mean_c( x[b,c,h,w] * y[b,c,h,w-d] ), 0 for w<d
// Fixed problem: B=8, C=32, H=256, W=512, D=48 (maxdisp)

constexpr int kB = 8;
constexpr int kC = 32;
constexpr int kH = 256;
constexpr int kW = 512;
constexpr int kD = 48;

constexpr int WT = 128;          // w-tile per block
constexpr int YW = kD + WT;      // 176: ys covers w0-48 .. w0+127
constexpr int NT = 192;          // threads: 16 w-groups x 12 d-groups

__global__ __launch_bounds__(NT) void corr_kernel(
    const float* __restrict__ x, const float* __restrict__ y, float* __restrict__ out)
{
    __shared__ __align__(16) float xs[kC][WT];   // 16 KB
    __shared__ __align__(16) float ys[kC][YW];   // 22.5 KB

    const int tid = threadIdx.x;
    const int w0 = blockIdx.x * WT;
    const int h  = blockIdx.y;
    const int b  = blockIdx.z;

    const size_t chan_stride = (size_t)kH * kW;
    const float* xb = x + ((size_t)b * kC * kH + h) * kW + w0;        // x[b][0][h][w0]
    const float* yb = y + ((size_t)b * kC * kH + h) * kW + (w0 - kD); // y[b][0][h][w0-48]

    // ---- stage x tile: 32 rows x 128 floats, coalesced float4 ----
    #pragma unroll 2
    for (int idx = tid; idx < kC * (WT / 4); idx += NT) {
        int c   = idx >> 5;            // WT/4 = 32 float4 per row
        int col = (idx & 31) << 2;
        float4 v = *(const float4*)(xb + (size_t)c * chan_stride + col);
        *(float4*)&xs[c][col] = v;
    }
    // ---- stage y tile: 32 rows x 176 floats (w0-48..w0+127), zero-fill w<0 ----
    #pragma unroll 2
    for (int idx = tid; idx < kC * (YW / 4); idx += NT) {
        int c   = idx / (YW / 4);      // YW/4 = 44 float4 per row
        int col = (idx % (YW / 4)) << 2;
        float4 v;
        if (w0 - kD + col >= 0) {
            v = *(const float4*)(yb + (size_t)c * chan_stride + col);
        } else {
            v = make_float4(0.f, 0.f, 0.f, 0.f);  // exact zeros -> out==0 for w<d
        }
        *(float4*)&ys[c][col] = v;
    }
    __syncthreads();

    // ---- compute: per-thread register tile 8w x 4d ----
    const int wg  = tid & 15;          // 16 w-groups
    const int dg  = tid >> 4;          // 12 d-groups
    const int wi  = wg << 3;           // 0..120
    const int db  = dg << 2;           // 0..44
    const int yb0 = wi + (kD - 4) - db; // aligned (mod 4) start of 12-word y window; >= 0

    float acc[4][8];
    #pragma unroll
    for (int dd = 0; dd < 4; ++dd)
        #pragma unroll
        for (int j = 0; j < 8; ++j) acc[dd][j] = 0.f;

    #pragma unroll 4
    for (int c = 0; c < kC; ++c) {
        float4 x0 = *(const float4*)&xs[c][wi];
        float4 x1 = *(const float4*)&xs[c][wi + 4];
        float4 y0 = *(const float4*)&ys[c][yb0];
        float4 y1 = *(const float4*)&ys[c][yb0 + 4];
        float4 y2 = *(const float4*)&ys[c][yb0 + 8];
        float xv[8]  = {x0.x, x0.y, x0.z, x0.w, x1.x, x1.y, x1.z, x1.w};
        float yv[12] = {y0.x, y0.y, y0.z, y0.w, y1.x, y1.y, y1.z, y1.w,
                        y2.x, y2.y, y2.z, y2.w};
        // out[d=db+dd][w=w0+wi+j] needs y[w - d] = ys[wi + j - db - dd + 48]
        //   = yv[(wi + 48 - db - dd + j) - yb0] = yv[4 - dd + j]   (compile-time index)
        #pragma unroll
        for (int dd = 0; dd < 4; ++dd)
            #pragma unroll
            for (int j = 0; j < 8; ++j)
                acc[dd][j] += xv[j] * yv[4 - dd + j];
    }

    // ---- epilogue: scale by 1/32, coalesced float4 stores ----
    const float scale = 1.0f / kC;
    #pragma unroll
    for (int dd = 0; dd < 4; ++dd) {
        int d = db + dd;
        float* o = out + (((size_t)b * kD + d) * kH + h) * kW + w0 + wi;
        float4 o0 = make_float4(acc[dd][0] * scale, acc[dd][1] * scale,
                                acc[dd][2] * scale, acc[dd][3] * scale);
        float4 o1 = make_float4(acc[dd][4] * scale, acc[dd][5] * scale,
                                acc[dd][6] * scale, acc[dd][7] * scale);
        *(float4*)(o)     = o0;
        *(float4*)(o + 4) = o1;
    }
}

extern "C" void kernel_launch(void* const* d_in, const int* in_sizes, int n_in,
                              void* d_out, int out_size, void* d_ws, size_t ws_size,
                              hipStream_t stream) {
    const float* x = (const float*)d_in[0];
    const float* y = (const float*)d_in[1];
    // d_in[2] is maxdisp (=48), baked in as kD
    float* out = (float*)d_out;

    dim3 grid(kW / WT, kH, kB);   // (4, 256, 8) = 8192 blocks
    corr_kernel<<<grid, NT, 0, stream>>>(x, y, out);
}

// Round 2
// 410.803 us; speedup vs baseline: 1.1064x; 1.1064x over previous
//
#include <hip/hip_runtime.h>

// Correlation cost volume: out[b,d,h,w] = mean_c( x[b,c,h,w] * y[b,c,h,w-d] ), 0 for w<d
// B=8, C=32, H=256, W=512, D=48
//
// R2: bank-conflict-free LDS mapping. Thread = (lw = tid&31 -> 4 consecutive w,
// dgrp = tid>>5 -> 12 d values). Consecutive lanes read consecutive 16B from LDS
// (canonical conflict-free ds_read_b128 pattern). Channels staged in two 16-c
// phases -> 19.25 KB LDS -> 8 blocks/CU.

constexpr int kB = 8;
constexpr int kC = 32;
constexpr int kH = 256;
constexpr int kW = 512;
constexpr int kD = 48;

constexpr int WT = 128;          // w-tile per block
constexpr int YW = kD + WT;      // 176 floats of y per row
constexpr int NT = 128;          // 2 waves
constexpr int CH = 16;           // channels per staging phase
constexpr int DP = 12;           // d per thread (4 d-groups)
constexpr int WP = 4;            // w per thread (32 w-chunks)

__global__ __launch_bounds__(NT) void corr_kernel(
    const float* __restrict__ x, const float* __restrict__ y, float* __restrict__ out)
{
    __shared__ __align__(16) float xs[CH][WT];   // 8 KB
    __shared__ __align__(16) float ys[CH][YW];   // 11.25 KB

    const int tid = threadIdx.x;
    const int w0  = blockIdx.x * WT;
    const int h   = blockIdx.y;
    const int b   = blockIdx.z;

    const size_t cs = (size_t)kH * kW;
    const float* xb = x + ((size_t)b * kC * kH + h) * kW + w0;        // x[b][0][h][w0]
    const float* yb = y + ((size_t)b * kC * kH + h) * kW + (w0 - kD); // y[b][0][h][w0-48]

    const int lw    = tid & 31;              // 32 w-chunks of 4
    const int dgrp  = tid >> 5;              // 4 d-groups of 12
    const int wi    = lw << 2;               // 0..124
    const int d0    = dgrp * DP;             // 0,12,24,36
    const int ybase = wi + 36 - d0;          // 4-aligned; covers yv[0..15], need [1..15]

    float acc[DP][WP];
    #pragma unroll
    for (int dd = 0; dd < DP; ++dd)
        #pragma unroll
        for (int j = 0; j < WP; ++j) acc[dd][j] = 0.f;

    for (int p = 0; p < 2; ++p) {
        if (p) __syncthreads();              // WAR: finish compute before restage

        // stage x: 16 rows x 128 floats; lane-contiguous float4 (conflict-free)
        #pragma unroll
        for (int idx = tid; idx < CH * (WT / 4); idx += NT) {
            int c   = idx >> 5;              // 32 float4 per row
            int col = (idx & 31) << 2;
            *(float4*)&xs[c][col] =
                *(const float4*)(xb + (size_t)(p * CH + c) * cs + col);
        }
        // stage y: 16 rows x 176 floats (w0-48..w0+127), zero-fill w<0
        #pragma unroll
        for (int idx = tid; idx < CH * (YW / 4); idx += NT) {
            int c   = idx / (YW / 4);        // 44 float4 per row
            int col = (idx % (YW / 4)) << 2;
            float4 v = make_float4(0.f, 0.f, 0.f, 0.f);
            if (w0 - kD + col >= 0)
                v = *(const float4*)(yb + (size_t)(p * CH + c) * cs + col);
            *(float4*)&ys[c][col] = v;
        }
        __syncthreads();

        // compute: per c, 1 x-read + 4 y-reads (all lane-contiguous b128), 48 FMAs
        #pragma unroll 4
        for (int c = 0; c < CH; ++c) {
            float4 x4 = *(const float4*)&xs[c][wi];
            float4 y0 = *(const float4*)&ys[c][ybase];
            float4 y1 = *(const float4*)&ys[c][ybase + 4];
            float4 y2 = *(const float4*)&ys[c][ybase + 8];
            float4 y3 = *(const float4*)&ys[c][ybase + 12];
            float xv[4]  = {x4.x, x4.y, x4.z, x4.w};
            float yv[16] = {y0.x, y0.y, y0.z, y0.w, y1.x, y1.y, y1.z, y1.w,
                            y2.x, y2.y, y2.z, y2.w, y3.x, y3.y, y3.z, y3.w};
            // out[d=d0+dd][w=w0+wi+j] needs ys col wi+j-(d0+dd)+48 -> yv[j+12-dd]
            #pragma unroll
            for (int dd = 0; dd < DP; ++dd)
                #pragma unroll
                for (int j = 0; j < WP; ++j)
                    acc[dd][j] += xv[j] * yv[j + 12 - dd];
        }
    }

    // epilogue: scale 1/32, coalesced float4 stores (lane-contiguous per d)
    const float scale = 1.0f / kC;
    #pragma unroll
    for (int dd = 0; dd < DP; ++dd) {
        float* o = out + (((size_t)b * kD + d0 + dd) * kH + h) * kW + w0 + wi;
        *(float4*)o = make_float4(acc[dd][0] * scale, acc[dd][1] * scale,
                                  acc[dd][2] * scale, acc[dd][3] * scale);
    }
}

extern "C" void kernel_launch(void* const* d_in, const int* in_sizes, int n_in,
                              void* d_out, int out_size, void* d_ws, size_t ws_size,
                              hipStream_t stream) {
    const float* x = (const float*)d_in[0];
    const float* y = (const float*)d_in[1];
    float* out = (float*)d_out;

    dim3 grid(kW / WT, kH, kB);   // (4, 256, 8) = 8192 blocks
    corr_kernel<<<grid, NT, 0, stream>>>(x, y, out);
}